// Round 7
// baseline (628.187 us; speedup 1.0000x reference)
//
#include <hip/hip_runtime.h>
#include <hip/hip_bf16.h>

#define BTOT 65536
#define DDIM 512
#define CDIM 1000
#define KSEL 45875   // int(65536 * 0.7)

#define L2E 1.44269504088896340736f
#define LN2 0.69314718055994530942f
#define NEG_BIG -1.0e30f

typedef __attribute__((ext_vector_type(8))) short short8;
typedef __attribute__((ext_vector_type(8))) unsigned short ushort8;
typedef __attribute__((ext_vector_type(4))) float f32x4;

__device__ __forceinline__ unsigned short f2bf(float f) {
  // round-to-nearest-even fp32 -> bf16, pure value-level bit ops
  unsigned u = __float_as_uint(f);
  u += 0x7FFFu + ((u >> 16) & 1u);
  return (unsigned short)(u >> 16);
}

// value-level f32x8 -> bf16x8: element inserts only (R2-proven scratch-free pattern)
__device__ __forceinline__ short8 cvt8(const float4 f0, const float4 f1) {
  short8 v;
  v[0] = (short)f2bf(f0.x); v[1] = (short)f2bf(f0.y);
  v[2] = (short)f2bf(f0.z); v[3] = (short)f2bf(f0.w);
  v[4] = (short)f2bf(f1.x); v[5] = (short)f2bf(f1.y);
  v[6] = (short)f2bf(f1.z); v[7] = (short)f2bf(f1.w);
  return v;
}

__device__ __forceinline__ void gload_lds16(const void* g, void* l) {
  __builtin_amdgcn_global_load_lds(
      (const __attribute__((address_space(1))) unsigned int*)g,
      (__attribute__((address_space(3))) unsigned int*)l, 16, 0, 0);
}

// ---- fused prep: B-panel images (swizzled) + hist zero + bias ----
// Panel p (0..7) holds cols [p*128, p*128+128) as [128 cols][512 k] bf16;
// element (cl,k) at byte ((cl<<10)|(k<<1)) ^ ((cl&7)<<4)  within the panel.
__global__ void prep_all(const float* __restrict__ W, const float* __restrict__ b,
                         unsigned short* __restrict__ Wg, float* __restrict__ bp,
                         unsigned* __restrict__ hzero) {
  const int bid = blockIdx.x, tid = threadIdx.x;
  if (bid < 256) {
    const int idx = bid * 256 + tid;      // 65536
    const int c  = idx & 1023;            // padded col
    const int k8 = idx >> 10;             // 0..63
    const int p = c >> 7, cl = c & 127;
    ushort8 v;
#pragma unroll
    for (int j = 0; j < 8; ++j) {
      const int k = k8 * 8 + j;
      v[j] = (c < CDIM) ? f2bf(W[k * CDIM + c]) : (unsigned short)0;
    }
    const unsigned off = ((((unsigned)cl) << 10) | (((unsigned)k8) << 4)) ^
                         ((((unsigned)cl) & 7u) << 4);
    *(ushort8*)((char*)Wg + (size_t)p * 131072 + off) = v;
  } else if (bid < 384) {
    ((uint4*)hzero)[(bid - 256) * 256 + tid] = (uint4){0, 0, 0, 0};  // 512 KiB (hHi+hLo)
  } else {
    for (int i = tid; i < 1024; i += 256) bp[i] = (i < CDIM) ? b[i] * L2E : NEG_BIG;
  }
}

// ---- persistent fused GEMM + partial fixed-max LSE ----
// 256 blocks (1/CU, LDS-capped) x 512 thr (8 waves). Block = (xcd-stripe, panel).
// B-panel staged ONCE into 128KB LDS; main loop barrier-free; 32 rows/wave/iter.
// DESIGN RULE (R2-R5 evidence): arch-VGPR cap is 128 here; acc[2][8]=64 regs
// + ag 8 + addressing keeps total < 128 -> no scratch spill.
__launch_bounds__(512, 1)
__global__ void ohem_losses(const float* __restrict__ feat,
                            const int* __restrict__ targets,
                            const unsigned short* __restrict__ Wg,
                            const float* __restrict__ bpad,
                            float* __restrict__ spart,
                            float* __restrict__ tvpart) {
  extern __shared__ char lbuf[];          // 131072 B
  const int tid = threadIdx.x, lane = tid & 63, w = tid >> 6;
  const int l15 = lane & 15, lgrp = lane >> 4;
  const int bid = blockIdx.x;
  const int xcd = bid & 7, q = bid >> 3;
  const int p = q & 7, stp8 = q >> 3;     // panel, stripe-slot
  const int gs = xcd * 4 + stp8;          // stripe 0..31 (8 panel-blocks share one XCD)
  const int rowS = gs << 11;              // *2048

  // stage panel p once: 131072 B = 16 iters x 512 thr x 16B (linear dest = swizzled image)
  const char* src = (const char*)Wg + (size_t)p * 131072;
#pragma unroll
  for (int r = 0; r < 16; ++r) {
    const int off = (r * 512 + tid) * 16;
    gload_lds16(src + off, lbuf + off);
  }

  __syncthreads();   // panel resident (drains vmcnt); the ONLY barrier

  const int p128 = p << 7;
  const unsigned xm   = ((unsigned)(l15 & 7)) << 4;
  const unsigned bofs = (((unsigned)l15) << 10) | (((unsigned)lgrp) << 4);

  for (int it = 0; it < 8; ++it) {
    const int rowB = rowS + (it << 8) + (w << 5);   // 32 rows for this wave
    const float* a0 = feat + (size_t)(rowB + l15) * DDIM + lgrp * 8;
    const float* a1 = a0 + 16 * DDIM;

    f32x4 acc[2][8];
#pragma unroll
    for (int rf = 0; rf < 2; ++rf)
#pragma unroll
      for (int cf = 0; cf < 8; ++cf) acc[rf][cf] = (f32x4){0.f, 0.f, 0.f, 0.f};

#pragma unroll
    for (int ks = 0; ks < 16; ++ks) {
      const float4 p00 = *(const float4*)(a0 + ks * 32);
      const float4 p01 = *(const float4*)(a0 + ks * 32 + 4);
      const float4 p10 = *(const float4*)(a1 + ks * 32);
      const float4 p11 = *(const float4*)(a1 + ks * 32 + 4);
      const short8 ag0 = cvt8(p00, p01);
      const short8 ag1 = cvt8(p10, p11);
      const unsigned kb = (bofs | ((unsigned)ks << 6)) ^ xm;
#pragma unroll
      for (int cf = 0; cf < 8; ++cf) {
        const short8 bfr = *(const short8*)(lbuf + kb + (unsigned)cf * 16384u);
        acc[0][cf] = __builtin_amdgcn_mfma_f32_16x16x32_bf16(ag0, bfr, acc[0][cf], 0, 0, 0);
        acc[1][cf] = __builtin_amdgcn_mfma_f32_16x16x32_bf16(ag1, bfr, acc[1][cf], 0, 0, 0);
      }
    }

    // partial LSE epilogue: C layout col = l15, row = lgrp*4 + reg
#pragma unroll
    for (int rf = 0; rf < 2; ++rf)
#pragma unroll
      for (int r = 0; r < 4; ++r) {
        const int row = rowB + rf * 16 + lgrp * 4 + r;
        const int tc = targets[row];
        float s = 0.f, tv = NEG_BIG;
#pragma unroll
        for (int cf = 0; cf < 8; ++cf) {
          const int col = p128 + cf * 16 + l15;
          const float z = fmaf(acc[rf][cf][r], L2E, bpad[col]);
          if (col == tc) tv = z;
          s += __builtin_amdgcn_exp2f(z);
        }
#pragma unroll
        for (int st = 1; st <= 8; st <<= 1) {
          s += __shfl_xor(s, st, 64);
          tv = fmaxf(tv, __shfl_xor(tv, st, 64));
        }
        if (l15 == 0) {
          spart[(size_t)p * BTOT + row]  = s;
          tvpart[(size_t)p * BTOT + row] = tv;
        }
      }
  }
}

// ---- combine 8 panel-partials -> loss, + hi-16 histogram ----
__global__ void combine_hist(const float* __restrict__ spart,
                             const float* __restrict__ tvpart,
                             float* __restrict__ losses,
                             unsigned* __restrict__ hHi) {
  const int row = blockIdx.x * 256 + threadIdx.x;
  float s = 0.f, tv = NEG_BIG;
#pragma unroll
  for (int p = 0; p < 8; ++p) {
    s  += spart[(size_t)p * BTOT + row];
    tv  = fmaxf(tv, tvpart[(size_t)p * BTOT + row]);
  }
  float loss = LN2 * (__builtin_amdgcn_logf(s) - tv);
  loss = fmaxf(loss, 0.f);
  losses[row] = loss;
  atomicAdd(&hHi[__float_as_uint(loss) >> 16], 1u);
}

// ---- level scan: find bin containing the k-th largest; 1 block x 256 threads ----
__global__ void scan_level(const unsigned* __restrict__ hist,
                           unsigned* __restrict__ state, const int level) {
  const int t = threadIdx.x;
  __shared__ unsigned sh[256];
  const unsigned k       = (level == 0) ? (unsigned)KSEL : state[1];
  const unsigned oldpref = (level == 0) ? 0u : state[0];

  unsigned gs = 0;
  const uint4* hp = (const uint4*)(hist + t * 256);
#pragma unroll 4
  for (int i = 0; i < 64; ++i) { const uint4 h = hp[i]; gs += h.x + h.y + h.z + h.w; }
  sh[t] = gs;
  __syncthreads();
  for (int off = 1; off < 256; off <<= 1) {   // inclusive suffix scan
    unsigned v = sh[t];
    if (t + off < 256) v += sh[t + off];
    __syncthreads();
    sh[t] = v;
    __syncthreads();
  }
  const unsigned incl  = sh[t];
  const unsigned above = (t < 255) ? sh[t + 1] : 0u;
  if (above < k && k <= incl) {          // exactly one thread
    unsigned kk = k - above;
    int bkt = 255;
    for (; bkt > 0; --bkt) {
      const unsigned c = hist[t * 256 + bkt];
      if (kk <= c) break;
      kk -= c;
    }
    const unsigned bin = (unsigned)(t * 256 + bkt);
    if (level == 0) { state[0] = bin << 16;      state[1] = kk; }
    else            { state[0] = oldpref | bin;  state[1] = kk; }
  }
}

__global__ void hist_lo(const float* __restrict__ losses,
                        const unsigned* __restrict__ state,
                        unsigned* __restrict__ hLo) {
  const unsigned pref = state[0] >> 16;
  const int i = blockIdx.x * 256 + threadIdx.x;
  const unsigned u = ((const unsigned*)losses)[i];
  if ((u >> 16) == pref) atomicAdd(&hLo[u & 0xFFFFu], 1u);
}

// ---- deterministic sum/count of values strictly greater than threshold ----
__global__ void ohem_sum(const float* __restrict__ losses,
                         const unsigned* __restrict__ state,
                         float* __restrict__ psum, unsigned* __restrict__ pcnt) {
  const unsigned ut = state[0];
  const int i = blockIdx.x * 256 + threadIdx.x;
  const float v = losses[i];
  const unsigned u = __float_as_uint(v);
  float    sv = (u > ut) ? v  : 0.f;
  unsigned sc = (u > ut) ? 1u : 0u;
#pragma unroll
  for (int st = 32; st >= 1; st >>= 1) {
    sv += __shfl_xor(sv, st, 64);
    sc += __shfl_xor(sc, st, 64);
  }
  __shared__ float    wsum[4];
  __shared__ unsigned wcnt[4];
  const int w = threadIdx.x >> 6;
  if ((threadIdx.x & 63) == 0) { wsum[w] = sv; wcnt[w] = sc; }
  __syncthreads();
  if (threadIdx.x == 0) {
    psum[blockIdx.x] = wsum[0] + wsum[1] + wsum[2] + wsum[3];
    pcnt[blockIdx.x] = wcnt[0] + wcnt[1] + wcnt[2] + wcnt[3];
  }
}

__global__ void ohem_final(const float* __restrict__ psum,
                           const unsigned* __restrict__ pcnt,
                           const unsigned* __restrict__ state,
                           float* __restrict__ out) {
  float    sv = psum[threadIdx.x];
  unsigned sc = pcnt[threadIdx.x];
#pragma unroll
  for (int st = 32; st >= 1; st >>= 1) {
    sv += __shfl_xor(sv, st, 64);
    sc += __shfl_xor(sc, st, 64);
  }
  __shared__ float    wsum[4];
  __shared__ unsigned wcnt[4];
  const int w = threadIdx.x >> 6;
  if ((threadIdx.x & 63) == 0) { wsum[w] = sv; wcnt[w] = sc; }
  __syncthreads();
  if (threadIdx.x == 0) {
    const float    sum = wsum[0] + wsum[1] + wsum[2] + wsum[3];
    const unsigned cnt = wcnt[0] + wcnt[1] + wcnt[2] + wcnt[3];
    const float t = __uint_as_float(state[0]);
    out[0] = (sum + (float)(KSEL - cnt) * t) / (float)KSEL;
  }
}

extern "C" void kernel_launch(void* const* d_in, const int* in_sizes, int n_in,
                              void* d_out, int out_size, void* d_ws, size_t ws_size,
                              hipStream_t stream) {
  const float* feat    = (const float*)d_in[0];
  const int*   targets = (const int*)d_in[1];
  const float* W       = (const float*)d_in[2];
  const float* b       = (const float*)d_in[3];
  float* out = (float*)d_out;

  char* ws = (char*)d_ws;
  unsigned short* Wg     = (unsigned short*)ws;              // 1 MiB (8 swizzled panels)
  float*          bp     = (float*)(ws + 1048576);           // 4 KiB
  float*          spart  = (float*)(ws + 1052672);           // 2 MiB
  float*          tvpart = (float*)(ws + 3149824);           // 2 MiB
  float*          losses = (float*)(ws + 5246976);           // 256 KiB
  unsigned*       hHi    = (unsigned*)(ws + 5509120);        // 256 KiB
  unsigned*       hLo    = (unsigned*)(ws + 5771264);        // 256 KiB (contiguous after hHi)
  unsigned*       state  = (unsigned*)(ws + 6033408);        // 256 B
  float*          psum   = (float*)(ws + 6033664);           // 1 KiB
  unsigned*       pcnt   = (unsigned*)(ws + 6034688);        // 1 KiB

  (void)hipFuncSetAttribute((const void*)ohem_losses,
                            hipFuncAttributeMaxDynamicSharedMemorySize, 131072);

  prep_all<<<385, 256, 0, stream>>>(W, b, Wg, bp, hHi);      // hHi..hLo zeroed
  ohem_losses<<<256, 512, 131072, stream>>>(feat, targets, Wg, bp, spart, tvpart);
  combine_hist<<<256, 256, 0, stream>>>(spart, tvpart, losses, hHi);
  scan_level<<<1, 256, 0, stream>>>(hHi, state, 0);
  hist_lo<<<256, 256, 0, stream>>>(losses, state, hLo);
  scan_level<<<1, 256, 0, stream>>>(hLo, state, 1);
  ohem_sum<<<256, 256, 0, stream>>>(losses, state, psum, pcnt);
  ohem_final<<<1, 256, 0, stream>>>(psum, pcnt, state, out);
}

// Round 8
// 342.960 us; speedup vs baseline: 1.8317x; 1.8317x over previous
//
#include <hip/hip_runtime.h>
#include <hip/hip_bf16.h>

#define BTOT 65536
#define DDIM 512
#define CDIM 1000
#define KSEL 45875   // int(65536 * 0.7)

#define L2E 1.44269504088896340736f
#define LN2 0.69314718055994530942f
#define NEG_BIG -1.0e30f

typedef __attribute__((ext_vector_type(8))) short short8;
typedef __attribute__((ext_vector_type(8))) unsigned short ushort8;
typedef __attribute__((ext_vector_type(4))) float f32x4;

__device__ __forceinline__ unsigned short f2bf(float f) {
  // round-to-nearest-even fp32 -> bf16, pure value-level bit ops
  unsigned u = __float_as_uint(f);
  u += 0x7FFFu + ((u >> 16) & 1u);
  return (unsigned short)(u >> 16);
}

// value-level f32x8 -> bf16x8: element inserts only (R2-proven scratch-free pattern)
__device__ __forceinline__ short8 cvt8(const float4 f0, const float4 f1) {
  short8 v;
  v[0] = (short)f2bf(f0.x); v[1] = (short)f2bf(f0.y);
  v[2] = (short)f2bf(f0.z); v[3] = (short)f2bf(f0.w);
  v[4] = (short)f2bf(f1.x); v[5] = (short)f2bf(f1.y);
  v[6] = (short)f2bf(f1.z); v[7] = (short)f2bf(f1.w);
  return v;
}

__device__ __forceinline__ void gload_lds16(const void* g, void* l) {
  __builtin_amdgcn_global_load_lds(
      (const __attribute__((address_space(1))) unsigned int*)g,
      (__attribute__((address_space(3))) unsigned int*)l, 16, 0, 0);
}

// ---- fused prep: Wt image (64 chunks x [16 cols][512 k] bf16, swizzled) + hist zero + bias ----
// Within chunk: element (cc,k) at byte ((cc<<10)|(k<<1)) ^ ((cc&7)<<4).
__global__ void prep_all(const float* __restrict__ W, const float* __restrict__ b,
                         unsigned short* __restrict__ Wg, float* __restrict__ bp,
                         unsigned* __restrict__ hzero) {
  const int bid = blockIdx.x, tid = threadIdx.x;
  if (bid < 256) {
    const int idx = bid * 256 + tid;      // 65536
    const int c  = idx & 1023;            // padded col
    const int k8 = idx >> 10;             // 0..63
    const int p = c >> 4, cc = c & 15;    // chunk, col-in-chunk
    ushort8 v;
#pragma unroll
    for (int j = 0; j < 8; ++j) {
      const int k = k8 * 8 + j;
      v[j] = (c < CDIM) ? f2bf(W[k * CDIM + c]) : (unsigned short)0;
    }
    const unsigned off = ((((unsigned)cc) << 10) | (((unsigned)k8) << 4)) ^
                         ((((unsigned)cc) & 7u) << 4);
    *(ushort8*)((char*)Wg + (size_t)p * 16384 + off) = v;
  } else if (bid < 384) {
    ((uint4*)hzero)[(bid - 256) * 256 + tid] = (uint4){0, 0, 0, 0};  // 512 KiB (hHi+hLo)
  } else {
    for (int i = tid; i < 1024; i += 256) bp[i] = (i < CDIM) ? b[i] * L2E : NEG_BIG;
  }
}

// ---- fused GEMM + fixed-max LSE + direct loss write + hi-16 histogram ----
// 1024 blocks x 128 thr (2 waves) -> 4 blocks/CU (LDS 36KB), 64 rows/block.
// Each wave: 32 rows in reg panel; sweeps 64 col-chunks of 16, B dbuf in LDS.
// A read exactly once (128 MB total); Wg (1MB) L2-resident -> drift harmless.
__launch_bounds__(128)
__global__ void ohem_losses(const float* __restrict__ feat,
                            const int* __restrict__ targets,
                            const unsigned short* __restrict__ Wg,
                            const float* __restrict__ bpad,
                            float* __restrict__ losses,
                            unsigned* __restrict__ histHi) {
  __shared__ char lbuf[2][16384];
  __shared__ float biasLds[1024];
  const int tid = threadIdx.x, lane = tid & 63, w = tid >> 6;
  const int l15 = lane & 15, lgrp = lane >> 4;
  const int rowB = blockIdx.x * 64 + w * 32;

  // bias -> LDS once
#pragma unroll
  for (int j = 0; j < 8; ++j) biasLds[tid * 8 + j] = bpad[tid * 8 + j];

  // stage chunk 0 into buf 0
#pragma unroll
  for (int r = 0; r < 8; ++r) {
    const int off = (r * 128 + tid) * 16;
    gload_lds16((const char*)Wg + off, &lbuf[0][0] + off);
  }

  // A panel: a[rf][ks] = rows rowB+rf*16+l15, k = ks*32 + lgrp*8 + j (64 VGPR)
  short8 a[2][16];
#pragma unroll
  for (int rf = 0; rf < 2; ++rf) {
    const float* src = feat + (size_t)(rowB + rf * 16 + l15) * DDIM + lgrp * 8;
#pragma unroll
    for (int ks = 0; ks < 16; ++ks) {
      const float4 f0 = *(const float4*)(src + ks * 32);
      const float4 f1 = *(const float4*)(src + ks * 32 + 4);
      a[rf][ks] = cvt8(f0, f1);
    }
  }

  // per-lane state: slot = rf*4 + r covers row rowB + rf*16 + lgrp*4 + r
  int   tcol[8];
  float s[8], tv[8];
#pragma unroll
  for (int rf = 0; rf < 2; ++rf)
#pragma unroll
    for (int r = 0; r < 4; ++r) {
      const int slot = rf * 4 + r;
      tcol[slot] = targets[rowB + rf * 16 + lgrp * 4 + r];
      s[slot] = 0.f; tv[slot] = NEG_BIG;
    }

  __syncthreads();   // chunk 0 + bias resident

  const unsigned xm   = ((unsigned)(l15 & 7)) << 4;
  const unsigned bofs = (((unsigned)l15) << 10) | (((unsigned)lgrp) << 4);

  for (int nc = 0; nc < 64; ++nc) {
    const int cur = nc & 1;
    if (nc + 1 < 64) {   // stage next chunk into the other buffer
      const char* src = (const char*)Wg + (size_t)(nc + 1) * 16384;
#pragma unroll
      for (int r = 0; r < 8; ++r) {
        const int off = (r * 128 + tid) * 16;
        gload_lds16(src + off, &lbuf[cur ^ 1][0] + off);
      }
    }

    f32x4 acc0 = (f32x4){0.f, 0.f, 0.f, 0.f};
    f32x4 acc1 = (f32x4){0.f, 0.f, 0.f, 0.f};
    const char* lb = &lbuf[cur][0];
#pragma unroll
    for (int ks = 0; ks < 16; ++ks) {
      const short8 b0 = *(const short8*)(lb + ((bofs | ((unsigned)ks << 6)) ^ xm));
      acc0 = __builtin_amdgcn_mfma_f32_16x16x32_bf16(a[0][ks], b0, acc0, 0, 0, 0);
      acc1 = __builtin_amdgcn_mfma_f32_16x16x32_bf16(a[1][ks], b0, acc1, 0, 0, 0);
    }

    const int col0 = (nc << 4) + l15;
    const float bb0 = biasLds[col0];
#pragma unroll
    for (int r = 0; r < 4; ++r) {
      const float z0 = fmaf(acc0[r], L2E, bb0);
      const float z1 = fmaf(acc1[r], L2E, bb0);
      if (col0 == tcol[r])     tv[r]     = z0;
      if (col0 == tcol[4 + r]) tv[4 + r] = z1;
      s[r]     += __builtin_amdgcn_exp2f(z0);
      s[4 + r] += __builtin_amdgcn_exp2f(z1);
    }

    __syncthreads();   // next chunk staged + all waves done reading cur
  }

  // merge (s, tv) across the 16-lane group (pure sums; tv held by one lane)
#pragma unroll
  for (int st = 1; st <= 8; st <<= 1)
#pragma unroll
    for (int slot = 0; slot < 8; ++slot) {
      s[slot] += __shfl_xor(s[slot], st, 64);
      tv[slot] = fmaxf(tv[slot], __shfl_xor(tv[slot], st, 64));
    }

  if (l15 == 0) {
#pragma unroll
    for (int rf = 0; rf < 2; ++rf)
#pragma unroll
      for (int r = 0; r < 4; ++r) {
        const int slot = rf * 4 + r;
        float loss = LN2 * (__builtin_amdgcn_logf(s[slot]) - tv[slot]);
        loss = fmaxf(loss, 0.f);
        losses[rowB + rf * 16 + lgrp * 4 + r] = loss;
        atomicAdd(&histHi[__float_as_uint(loss) >> 16], 1u);
      }
  }
}

// NOTE (epilogue slot mapping): acc0 covers rows rf=0 (slots 0..3), acc1 rf=1
// (slots 4..7); tv/s indexed accordingly above.

// ---- level scan: find bin containing the k-th largest; 1 block x 256 threads ----
__global__ void scan_level(const unsigned* __restrict__ hist,
                           unsigned* __restrict__ state, const int level) {
  const int t = threadIdx.x;
  __shared__ unsigned sh[256];
  const unsigned k       = (level == 0) ? (unsigned)KSEL : state[1];
  const unsigned oldpref = (level == 0) ? 0u : state[0];

  unsigned gs = 0;
  const uint4* hp = (const uint4*)(hist + t * 256);
#pragma unroll 4
  for (int i = 0; i < 64; ++i) { const uint4 h = hp[i]; gs += h.x + h.y + h.z + h.w; }
  sh[t] = gs;
  __syncthreads();
  for (int off = 1; off < 256; off <<= 1) {   // inclusive suffix scan
    unsigned v = sh[t];
    if (t + off < 256) v += sh[t + off];
    __syncthreads();
    sh[t] = v;
    __syncthreads();
  }
  const unsigned incl  = sh[t];
  const unsigned above = (t < 255) ? sh[t + 1] : 0u;
  if (above < k && k <= incl) {          // exactly one thread
    unsigned kk = k - above;
    int bkt = 255;
    for (; bkt > 0; --bkt) {
      const unsigned c = hist[t * 256 + bkt];
      if (kk <= c) break;
      kk -= c;
    }
    const unsigned bin = (unsigned)(t * 256 + bkt);
    if (level == 0) { state[0] = bin << 16;      state[1] = kk; }
    else            { state[0] = oldpref | bin;  state[1] = kk; }
  }
}

__global__ void hist_lo(const float* __restrict__ losses,
                        const unsigned* __restrict__ state,
                        unsigned* __restrict__ hLo) {
  const unsigned pref = state[0] >> 16;
  const int i = blockIdx.x * 256 + threadIdx.x;
  const unsigned u = ((const unsigned*)losses)[i];
  if ((u >> 16) == pref) atomicAdd(&hLo[u & 0xFFFFu], 1u);
}

// ---- deterministic sum/count of values strictly greater than threshold ----
__global__ void ohem_sum(const float* __restrict__ losses,
                         const unsigned* __restrict__ state,
                         float* __restrict__ psum, unsigned* __restrict__ pcnt) {
  const unsigned ut = state[0];
  const int i = blockIdx.x * 256 + threadIdx.x;
  const float v = losses[i];
  const unsigned u = __float_as_uint(v);
  float    sv = (u > ut) ? v  : 0.f;
  unsigned sc = (u > ut) ? 1u : 0u;
#pragma unroll
  for (int st = 32; st >= 1; st >>= 1) {
    sv += __shfl_xor(sv, st, 64);
    sc += __shfl_xor(sc, st, 64);
  }
  __shared__ float    wsum[4];
  __shared__ unsigned wcnt[4];
  const int w = threadIdx.x >> 6;
  if ((threadIdx.x & 63) == 0) { wsum[w] = sv; wcnt[w] = sc; }
  __syncthreads();
  if (threadIdx.x == 0) {
    psum[blockIdx.x] = wsum[0] + wsum[1] + wsum[2] + wsum[3];
    pcnt[blockIdx.x] = wcnt[0] + wcnt[1] + wcnt[2] + wcnt[3];
  }
}

__global__ void ohem_final(const float* __restrict__ psum,
                           const unsigned* __restrict__ pcnt,
                           const unsigned* __restrict__ state,
                           float* __restrict__ out) {
  float    sv = psum[threadIdx.x];
  unsigned sc = pcnt[threadIdx.x];
#pragma unroll
  for (int st = 32; st >= 1; st >>= 1) {
    sv += __shfl_xor(sv, st, 64);
    sc += __shfl_xor(sc, st, 64);
  }
  __shared__ float    wsum[4];
  __shared__ unsigned wcnt[4];
  const int w = threadIdx.x >> 6;
  if ((threadIdx.x & 63) == 0) { wsum[w] = sv; wcnt[w] = sc; }
  __syncthreads();
  if (threadIdx.x == 0) {
    const float    sum = wsum[0] + wsum[1] + wsum[2] + wsum[3];
    const unsigned cnt = wcnt[0] + wcnt[1] + wcnt[2] + wcnt[3];
    const float t = __uint_as_float(state[0]);
    out[0] = (sum + (float)(KSEL - cnt) * t) / (float)KSEL;
  }
}

extern "C" void kernel_launch(void* const* d_in, const int* in_sizes, int n_in,
                              void* d_out, int out_size, void* d_ws, size_t ws_size,
                              hipStream_t stream) {
  const float* feat    = (const float*)d_in[0];
  const int*   targets = (const int*)d_in[1];
  const float* W       = (const float*)d_in[2];
  const float* b       = (const float*)d_in[3];
  float* out = (float*)d_out;

  char* ws = (char*)d_ws;
  unsigned short* Wg     = (unsigned short*)ws;              // 1 MiB (64 swizzled 16-col chunks)
  float*          bp     = (float*)(ws + 1048576);           // 4 KiB
  float*          losses = (float*)(ws + 1052672);           // 256 KiB
  unsigned*       hHi    = (unsigned*)(ws + 1314816);        // 256 KiB
  unsigned*       hLo    = (unsigned*)(ws + 1576960);        // 256 KiB (contiguous after hHi)
  unsigned*       state  = (unsigned*)(ws + 1839104);        // 256 B
  float*          psum   = (float*)(ws + 1839360);           // 1 KiB
  unsigned*       pcnt   = (unsigned*)(ws + 1840384);        // 1 KiB

  prep_all<<<385, 256, 0, stream>>>(W, b, Wg, bp, hHi);      // hHi..hLo zeroed
  ohem_losses<<<1024, 128, 0, stream>>>(feat, targets, Wg, bp, losses, hHi);
  scan_level<<<1, 256, 0, stream>>>(hHi, state, 0);
  hist_lo<<<256, 256, 0, stream>>>(losses, state, hLo);
  scan_level<<<1, 256, 0, stream>>>(hLo, state, 1);
  ohem_sum<<<256, 256, 0, stream>>>(losses, state, psum, pcnt);
  ohem_final<<<1, 256, 0, stream>>>(psum, pcnt, state, out);
}

// Round 9
// 310.541 us; speedup vs baseline: 2.0229x; 1.1044x over previous
//
#include <hip/hip_runtime.h>
#include <hip/hip_bf16.h>

#define BTOT 65536
#define DDIM 512
#define CDIM 1000
#define KSEL 45875   // int(65536 * 0.7)

#define L2E 1.44269504088896340736f
#define LN2 0.69314718055994530942f
#define NEG_BIG -1.0e30f

typedef __attribute__((ext_vector_type(8))) short short8;
typedef __attribute__((ext_vector_type(8))) unsigned short ushort8;
typedef __attribute__((ext_vector_type(4))) float f32x4;

__device__ __forceinline__ unsigned short f2bf(float f) {
  // round-to-nearest-even fp32 -> bf16, pure value-level bit ops
  unsigned u = __float_as_uint(f);
  u += 0x7FFFu + ((u >> 16) & 1u);
  return (unsigned short)(u >> 16);
}

// value-level f32x8 -> bf16x8: element inserts only (R2/R8-proven scratch-free)
__device__ __forceinline__ short8 cvt8(const float4 f0, const float4 f1) {
  short8 v;
  v[0] = (short)f2bf(f0.x); v[1] = (short)f2bf(f0.y);
  v[2] = (short)f2bf(f0.z); v[3] = (short)f2bf(f0.w);
  v[4] = (short)f2bf(f1.x); v[5] = (short)f2bf(f1.y);
  v[6] = (short)f2bf(f1.z); v[7] = (short)f2bf(f1.w);
  return v;
}

__device__ __forceinline__ void gload_lds16(const void* g, void* l) {
  __builtin_amdgcn_global_load_lds(
      (const __attribute__((address_space(1))) unsigned int*)g,
      (__attribute__((address_space(3))) unsigned int*)l, 16, 0, 0);
}

// ---- fused prep: Wg image (32 chunks x [32 cols][512 k] bf16, swizzled) + hist zero + bias ----
// Within chunk: element (cc,k) at byte ((cc<<10)|(k<<1)) ^ ((cc&7)<<4)  (R2-proven layout).
__global__ void prep_all(const float* __restrict__ W, const float* __restrict__ b,
                         unsigned short* __restrict__ Wg, float* __restrict__ bp,
                         unsigned* __restrict__ hzero) {
  const int bid = blockIdx.x, tid = threadIdx.x;
  if (bid < 256) {
    const int idx = bid * 256 + tid;      // 65536
    const int c  = idx & 1023;            // padded col
    const int k8 = idx >> 10;             // 0..63
    const int p = c >> 5, cc = c & 31;    // chunk, col-in-chunk
    ushort8 v;
#pragma unroll
    for (int j = 0; j < 8; ++j) {
      const int k = k8 * 8 + j;
      v[j] = (c < CDIM) ? f2bf(W[k * CDIM + c]) : (unsigned short)0;
    }
    const unsigned off = ((((unsigned)cc) << 10) | (((unsigned)k8) << 4)) ^
                         ((((unsigned)cc) & 7u) << 4);
    *(ushort8*)((char*)Wg + (size_t)p * 32768 + off) = v;
  } else if (bid < 384) {
    ((uint4*)hzero)[(bid - 256) * 256 + tid] = (uint4){0, 0, 0, 0};  // 512 KiB (hHi+hLo)
  } else {
    for (int i = tid; i < 1024; i += 256) bp[i] = (i < CDIM) ? b[i] * L2E : NEG_BIG;
  }
}

// ---- fused GEMM + fixed-max LSE + direct loss write + hi-16 histogram ----
// 512 blocks x 512 thr (8 waves); wave owns 16 rows (panel 64 VGPR); block = 128 rows.
// 2 blocks/CU (68 KB LDS) -> 16 waves/CU = 4/SIMD (the R1-R8 fix: was 2/SIMD).
// Sweeps 32 col-chunks of 32, B dbuf in LDS; A read exactly once.
__launch_bounds__(512, 2)   // 2048/(2 blk x 8 waves) = hard 128-VGPR cap (R1-R5 semantics)
__global__ void ohem_losses(const float* __restrict__ feat,
                            const int* __restrict__ targets,
                            const unsigned short* __restrict__ Wg,
                            const float* __restrict__ bpad,
                            float* __restrict__ losses,
                            unsigned* __restrict__ histHi) {
  __shared__ char lbuf[2][32768];
  __shared__ float biasLds[1024];
  const int tid = threadIdx.x, lane = tid & 63, w = tid >> 6;
  const int l15 = lane & 15, lgrp = lane >> 4;
  const int rowW = blockIdx.x * 128 + w * 16;   // wave's 16 rows

  // bias -> LDS once
  biasLds[tid * 2]     = bpad[tid * 2];
  biasLds[tid * 2 + 1] = bpad[tid * 2 + 1];

  // stage chunk 0 into buf 0: 32768 B = 4 x 512 thr x 16 B
#pragma unroll
  for (int r = 0; r < 4; ++r) {
    const int off = (r * 512 + tid) * 16;
    gload_lds16((const char*)Wg + off, &lbuf[0][0] + off);
  }

  // A panel: a[ks] = row rowW+l15, k = ks*32 + lgrp*8 + j  (64 VGPR)
  short8 a[16];
  {
    const float* src = feat + (size_t)(rowW + l15) * DDIM + lgrp * 8;
#pragma unroll
    for (int ks = 0; ks < 16; ++ks) {
      const float4 f0 = *(const float4*)(src + ks * 32);
      const float4 f1 = *(const float4*)(src + ks * 32 + 4);
      a[ks] = cvt8(f0, f1);
    }
  }

  // per-lane state: slot r covers row rowW + lgrp*4 + r
  int   tcol[4];
  float s[4], tv[4];
#pragma unroll
  for (int r = 0; r < 4; ++r) {
    tcol[r] = targets[rowW + lgrp * 4 + r];
    s[r] = 0.f; tv[r] = NEG_BIG;
  }

  __syncthreads();   // chunk 0 + bias resident

  const unsigned xm   = ((unsigned)(l15 & 7)) << 4;
  const unsigned bofs = (((unsigned)l15) << 10) | (((unsigned)lgrp) << 4);

  for (int nc = 0; nc < 32; ++nc) {
    const int cur = nc & 1;
    if (nc + 1 < 32) {   // stage next chunk into the other buffer
      const char* src = (const char*)Wg + (size_t)(nc + 1) * 32768;
#pragma unroll
      for (int r = 0; r < 4; ++r) {
        const int off = (r * 512 + tid) * 16;
        gload_lds16(src + off, &lbuf[cur ^ 1][0] + off);
      }
    }

    f32x4 acc0 = (f32x4){0.f, 0.f, 0.f, 0.f};   // cols nc*32 + l15
    f32x4 acc1 = (f32x4){0.f, 0.f, 0.f, 0.f};   // cols nc*32 + 16 + l15
    const char* lb = &lbuf[cur][0];
#pragma unroll
    for (int ks = 0; ks < 16; ++ks) {
      const unsigned o0 = (bofs | ((unsigned)ks << 6)) ^ xm;
      const short8 b0 = *(const short8*)(lb + o0);
      const short8 b1 = *(const short8*)(lb + o0 + 16384u);
      acc0 = __builtin_amdgcn_mfma_f32_16x16x32_bf16(a[ks], b0, acc0, 0, 0, 0);
      acc1 = __builtin_amdgcn_mfma_f32_16x16x32_bf16(a[ks], b1, acc1, 0, 0, 0);
    }

    const int col0 = (nc << 5) + l15;
    const int col1 = col0 + 16;
    const float bb0 = biasLds[col0];
    const float bb1 = biasLds[col1];
#pragma unroll
    for (int r = 0; r < 4; ++r) {
      const float z0 = fmaf(acc0[r], L2E, bb0);
      const float z1 = fmaf(acc1[r], L2E, bb1);
      if (col0 == tcol[r]) tv[r] = z0;
      if (col1 == tcol[r]) tv[r] = z1;
      s[r] += __builtin_amdgcn_exp2f(z0) + __builtin_amdgcn_exp2f(z1);
    }

    __syncthreads();   // next chunk staged + all waves done reading cur
  }

  // merge (s, tv) across the 16-lane col group (pure sums; tv held by one lane)
#pragma unroll
  for (int st = 1; st <= 8; st <<= 1)
#pragma unroll
    for (int r = 0; r < 4; ++r) {
      s[r] += __shfl_xor(s[r], st, 64);
      tv[r] = fmaxf(tv[r], __shfl_xor(tv[r], st, 64));
    }

  if (l15 == 0) {
#pragma unroll
    for (int r = 0; r < 4; ++r) {
      float loss = LN2 * (__builtin_amdgcn_logf(s[r]) - tv[r]);
      loss = fmaxf(loss, 0.f);
      losses[rowW + lgrp * 4 + r] = loss;
      atomicAdd(&histHi[__float_as_uint(loss) >> 16], 1u);
    }
  }
}

// ---- level scan: find bin containing the k-th largest; 1 block x 256 threads ----
__global__ void scan_level(const unsigned* __restrict__ hist,
                           unsigned* __restrict__ state, const int level) {
  const int t = threadIdx.x;
  __shared__ unsigned sh[256];
  const unsigned k       = (level == 0) ? (unsigned)KSEL : state[1];
  const unsigned oldpref = (level == 0) ? 0u : state[0];

  unsigned gs = 0;
  const uint4* hp = (const uint4*)(hist + t * 256);
#pragma unroll 4
  for (int i = 0; i < 64; ++i) { const uint4 h = hp[i]; gs += h.x + h.y + h.z + h.w; }
  sh[t] = gs;
  __syncthreads();
  for (int off = 1; off < 256; off <<= 1) {   // inclusive suffix scan
    unsigned v = sh[t];
    if (t + off < 256) v += sh[t + off];
    __syncthreads();
    sh[t] = v;
    __syncthreads();
  }
  const unsigned incl  = sh[t];
  const unsigned above = (t < 255) ? sh[t + 1] : 0u;
  if (above < k && k <= incl) {          // exactly one thread
    unsigned kk = k - above;
    int bkt = 255;
    for (; bkt > 0; --bkt) {
      const unsigned c = hist[t * 256 + bkt];
      if (kk <= c) break;
      kk -= c;
    }
    const unsigned bin = (unsigned)(t * 256 + bkt);
    if (level == 0) { state[0] = bin << 16;      state[1] = kk; }
    else            { state[0] = oldpref | bin;  state[1] = kk; }
  }
}

__global__ void hist_lo(const float* __restrict__ losses,
                        const unsigned* __restrict__ state,
                        unsigned* __restrict__ hLo) {
  const unsigned pref = state[0] >> 16;
  const int i = blockIdx.x * 256 + threadIdx.x;
  const unsigned u = ((const unsigned*)losses)[i];
  if ((u >> 16) == pref) atomicAdd(&hLo[u & 0xFFFFu], 1u);
}

// ---- deterministic sum/count of values strictly greater than threshold ----
__global__ void ohem_sum(const float* __restrict__ losses,
                         const unsigned* __restrict__ state,
                         float* __restrict__ psum, unsigned* __restrict__ pcnt) {
  const unsigned ut = state[0];
  const int i = blockIdx.x * 256 + threadIdx.x;
  const float v = losses[i];
  const unsigned u = __float_as_uint(v);
  float    sv = (u > ut) ? v  : 0.f;
  unsigned sc = (u > ut) ? 1u : 0u;
#pragma unroll
  for (int st = 32; st >= 1; st >>= 1) {
    sv += __shfl_xor(sv, st, 64);
    sc += __shfl_xor(sc, st, 64);
  }
  __shared__ float    wsum[4];
  __shared__ unsigned wcnt[4];
  const int w = threadIdx.x >> 6;
  if ((threadIdx.x & 63) == 0) { wsum[w] = sv; wcnt[w] = sc; }
  __syncthreads();
  if (threadIdx.x == 0) {
    psum[blockIdx.x] = wsum[0] + wsum[1] + wsum[2] + wsum[3];
    pcnt[blockIdx.x] = wcnt[0] + wcnt[1] + wcnt[2] + wcnt[3];
  }
}

__global__ void ohem_final(const float* __restrict__ psum,
                           const unsigned* __restrict__ pcnt,
                           const unsigned* __restrict__ state,
                           float* __restrict__ out) {
  float    sv = psum[threadIdx.x];
  unsigned sc = pcnt[threadIdx.x];
#pragma unroll
  for (int st = 32; st >= 1; st >>= 1) {
    sv += __shfl_xor(sv, st, 64);
    sc += __shfl_xor(sc, st, 64);
  }
  __shared__ float    wsum[4];
  __shared__ unsigned wcnt[4];
  const int w = threadIdx.x >> 6;
  if ((threadIdx.x & 63) == 0) { wsum[w] = sv; wcnt[w] = sc; }
  __syncthreads();
  if (threadIdx.x == 0) {
    const float    sum = wsum[0] + wsum[1] + wsum[2] + wsum[3];
    const unsigned cnt = wcnt[0] + wcnt[1] + wcnt[2] + wcnt[3];
    const float t = __uint_as_float(state[0]);
    out[0] = (sum + (float)(KSEL - cnt) * t) / (float)KSEL;
  }
}

extern "C" void kernel_launch(void* const* d_in, const int* in_sizes, int n_in,
                              void* d_out, int out_size, void* d_ws, size_t ws_size,
                              hipStream_t stream) {
  const float* feat    = (const float*)d_in[0];
  const int*   targets = (const int*)d_in[1];
  const float* W       = (const float*)d_in[2];
  const float* b       = (const float*)d_in[3];
  float* out = (float*)d_out;

  char* ws = (char*)d_ws;
  unsigned short* Wg     = (unsigned short*)ws;              // 1 MiB (32 swizzled 32-col chunks)
  float*          bp     = (float*)(ws + 1048576);           // 4 KiB
  float*          losses = (float*)(ws + 1052672);           // 256 KiB
  unsigned*       hHi    = (unsigned*)(ws + 1314816);        // 256 KiB
  unsigned*       hLo    = (unsigned*)(ws + 1576960);        // 256 KiB (contiguous after hHi)
  unsigned*       state  = (unsigned*)(ws + 1839104);        // 256 B
  float*          psum   = (float*)(ws + 1839360);           // 1 KiB
  unsigned*       pcnt   = (unsigned*)(ws + 1840384);        // 1 KiB

  prep_all<<<385, 256, 0, stream>>>(W, b, Wg, bp, hHi);      // hHi..hLo zeroed
  ohem_losses<<<512, 512, 0, stream>>>(feat, targets, Wg, bp, losses, hHi);
  scan_level<<<1, 256, 0, stream>>>(hHi, state, 0);
  hist_lo<<<256, 256, 0, stream>>>(losses, state, hLo);
  scan_level<<<1, 256, 0, stream>>>(hLo, state, 1);
  ohem_sum<<<256, 256, 0, stream>>>(losses, state, psum, pcnt);
  ohem_final<<<1, 256, 0, stream>>>(psum, pcnt, state, out);
}

// Round 10
// 305.211 us; speedup vs baseline: 2.0582x; 1.0175x over previous
//
#include <hip/hip_runtime.h>
#include <hip/hip_bf16.h>

#define BTOT 65536
#define DDIM 512
#define CDIM 1000
#define KSEL 45875   // int(65536 * 0.7)

#define L2E 1.44269504088896340736f
#define LN2 0.69314718055994530942f
#define NEG_BIG -1.0e30f

typedef __attribute__((ext_vector_type(8))) short short8;
typedef __attribute__((ext_vector_type(8))) unsigned short ushort8;
typedef __attribute__((ext_vector_type(4))) float f32x4;

__device__ __forceinline__ unsigned short f2bf(float f) {
  unsigned u = __float_as_uint(f);
  u += 0x7FFFu + ((u >> 16) & 1u);
  return (unsigned short)(u >> 16);
}

__device__ __forceinline__ short8 cvt8(const float4 f0, const float4 f1) {
  short8 v;
  v[0] = (short)f2bf(f0.x); v[1] = (short)f2bf(f0.y);
  v[2] = (short)f2bf(f0.z); v[3] = (short)f2bf(f0.w);
  v[4] = (short)f2bf(f1.x); v[5] = (short)f2bf(f1.y);
  v[6] = (short)f2bf(f1.z); v[7] = (short)f2bf(f1.w);
  return v;
}

__device__ __forceinline__ void gload_lds16(const void* g, void* l) {
  __builtin_amdgcn_global_load_lds(
      (const __attribute__((address_space(1))) unsigned int*)g,
      (__attribute__((address_space(3))) unsigned int*)l, 16, 0, 0);
}

// ---- prep: Wg = 8 cb x 8 tstep x [128 col][8 kslot][16B] bf16, PRE-SWIZZLED so that
// gload_lds copies it LINEARLY into LDS and the swizzled ds_read (byte ^ ((col&7)<<4))
// recovers W[k][col]. Content at (cb,t,col,kslot) = W[t*64 + (kslot^(col&7))*8 + j][cb*128+col].
__global__ void prep_all(const float* __restrict__ W, const float* __restrict__ b,
                         unsigned short* __restrict__ Wg, float* __restrict__ bp,
                         unsigned* __restrict__ hzero) {
  const int bid = blockIdx.x, tid = threadIdx.x;
  if (bid < 256) {
    const int idx = bid * 256 + tid;        // 65536 ushort8 slots
    const int c   = idx & 1023;             // padded global col
    const int q   = idx >> 10;              // 0..63
    const int t   = q >> 3, kslot = q & 7;
    const int cb  = c >> 7, col = c & 127;
    const int kb  = t * 64 + (kslot ^ (col & 7)) * 8;
    ushort8 v;
#pragma unroll
    for (int j = 0; j < 8; ++j)
      v[j] = (c < CDIM) ? f2bf(W[(kb + j) * CDIM + c]) : (unsigned short)0;
    *(ushort8*)((char*)Wg + (size_t)(cb * 8 + t) * 16384 + col * 128 + kslot * 16) = v;
  } else if (bid < 384) {
    ((uint4*)hzero)[(bid - 256) * 256 + tid] = (uint4){0, 0, 0, 0};  // 512 KiB (hHi+hLo)
  } else {
    for (int i = tid; i < 1024; i += 256) bp[i] = (i < CDIM) ? b[i] * L2E : NEG_BIG;
  }
}

// ---- K-inner-loop tiled GEMM (m97/m230 structure) + fused fixed-max LSE epilogue ----
// 4096 blocks x 256 thr (4 waves, 2x2). Tile 128x128, BK=64, 8 dbuf K-steps, 1 sync/step.
// rb = bid&511 (rows), cb = bid>>9 (col panel) -> 512 consecutive blocks share one B panel.
__launch_bounds__(256, 2)   // 2 blocks/CU -> 8 waves/CU -> 256-VGPR budget
__global__ void ohem_gemm(const float* __restrict__ feat,
                          const int* __restrict__ targets,
                          const unsigned short* __restrict__ Wg,
                          const float* __restrict__ bpad,
                          float2* __restrict__ part) {
  __shared__ char lbufA[2][16384];
  __shared__ char lbufB[2][16384];
  const int tid = threadIdx.x, lane = tid & 63, w = tid >> 6;
  const int l15 = lane & 15, lgrp = lane >> 4;
  const int wr = w >> 1, wc = w & 1;        // 2x2 wave grid
  const int rb = blockIdx.x & 511, cb = blockIdx.x >> 9;
  const int rowb = rb * 128;
  const int colb = cb * 128;
  const unsigned char* wgt = (const unsigned char*)Wg + (size_t)cb * 131072;

  // thread's 4 staging slots: slot = p*256+tid -> row = slot>>3, kslot = slot&7
  const int srow0 = tid >> 3, skslot = tid & 7;

  // ---- prologue: stage step 0 ----
  float4 af0[4][2];
#pragma unroll
  for (int p = 0; p < 4; ++p) {
    const int row = srow0 + p * 32;
    const float* sp = feat + (size_t)(rowb + row) * DDIM + skslot * 8;
    af0[p][0] = *(const float4*)sp;
    af0[p][1] = *(const float4*)(sp + 4);
  }
#pragma unroll
  for (int p = 0; p < 4; ++p)
    gload_lds16(wgt + (p * 256 + tid) * 16, &lbufB[0][0] + (p * 256 + tid) * 16);
#pragma unroll
  for (int p = 0; p < 4; ++p) {
    const int row = srow0 + p * 32;
    const unsigned db = (unsigned)(row * 128) + (((unsigned)skslot * 16) ^ (((unsigned)row & 7u) << 4));
    *(short8*)(&lbufA[0][0] + db) = cvt8(af0[p][0], af0[p][1]);
  }
  __syncthreads();

  f32x4 acc[4][4];
#pragma unroll
  for (int rf = 0; rf < 4; ++rf)
#pragma unroll
    for (int cf = 0; cf < 4; ++cf) acc[rf][cf] = (f32x4){0.f, 0.f, 0.f, 0.f};

  // ---- K loop: 8 steps of 64 ----
  for (int t = 0; t < 8; ++t) {
    const int cur = t & 1;
    float4 afn[4][2];
    if (t < 7) {
      // issue A global reads for t+1 (in flight during MFMA phase)
#pragma unroll
      for (int p = 0; p < 4; ++p) {
        const int row = srow0 + p * 32;
        const float* sp = feat + (size_t)(rowb + row) * DDIM + (t + 1) * 64 + skslot * 8;
        afn[p][0] = *(const float4*)sp;
        afn[p][1] = *(const float4*)(sp + 4);
      }
      // B for t+1 via gload_lds (linear copy of pre-swizzled image)
      const unsigned char* src = wgt + (size_t)(t + 1) * 16384;
#pragma unroll
      for (int p = 0; p < 4; ++p)
        gload_lds16(src + (p * 256 + tid) * 16, &lbufB[cur ^ 1][0] + (p * 256 + tid) * 16);
    }

    // compute on buf cur
    const char* lA = &lbufA[cur][0];
    const char* lB = &lbufB[cur][0];
#pragma unroll
    for (int ks = 0; ks < 2; ++ks) {
      short8 af[4], bf[4];
#pragma unroll
      for (int rf = 0; rf < 4; ++rf) {
        const int row = wr * 64 + rf * 16 + l15;
        const unsigned ba = (unsigned)(row * 128 + ks * 64 + lgrp * 16) ^ (((unsigned)row & 7u) << 4);
        af[rf] = *(const short8*)(lA + ba);
      }
#pragma unroll
      for (int cf = 0; cf < 4; ++cf) {
        const int col = wc * 64 + cf * 16 + l15;
        const unsigned bb = (unsigned)(col * 128 + ks * 64 + lgrp * 16) ^ (((unsigned)col & 7u) << 4);
        bf[cf] = *(const short8*)(lB + bb);
      }
#pragma unroll
      for (int rf = 0; rf < 4; ++rf)
#pragma unroll
        for (int cf = 0; cf < 4; ++cf)
          acc[rf][cf] = __builtin_amdgcn_mfma_f32_16x16x32_bf16(af[rf], bf[cf], acc[rf][cf], 0, 0, 0);
    }

    // write A(t+1) after compute (loads have landed by now)
    if (t < 7) {
#pragma unroll
      for (int p = 0; p < 4; ++p) {
        const int row = srow0 + p * 32;
        const unsigned db = (unsigned)(row * 128) + (((unsigned)skslot * 16) ^ (((unsigned)row & 7u) << 4));
        *(short8*)(&lbufA[cur ^ 1][0] + db) = cvt8(afn[p][0], afn[p][1]);
      }
    }
    __syncthreads();
  }

  // ---- fused LSE epilogue: per-lane exp-sums over this wave's 64 cols ----
  float s16[4][4], tv16[4][4];
#pragma unroll
  for (int rf = 0; rf < 4; ++rf)
#pragma unroll
    for (int r = 0; r < 4; ++r) {
      const int row = rowb + wr * 64 + rf * 16 + lgrp * 4 + r;
      const int tc = targets[row];
      float s = 0.f, tv = NEG_BIG;
#pragma unroll
      for (int cf = 0; cf < 4; ++cf) {
        const int col = colb + wc * 64 + cf * 16 + l15;
        const float z = fmaf(acc[rf][cf][r], L2E, bpad[col]);
        if (col == tc) tv = z;
        s += __builtin_amdgcn_exp2f(z);
      }
#pragma unroll
      for (int st = 1; st <= 8; st <<= 1) {
        s += __shfl_xor(s, st, 64);
        tv = fmaxf(tv, __shfl_xor(tv, st, 64));
      }
      s16[rf][r] = s; tv16[rf][r] = tv;
    }

  // merge the two wc-waves through LDS -> one partial per row per 128-col panel
  float* sM = (float*)&lbufA[0][0];       // 128 floats
  float* tM = (float*)&lbufA[0][512];     // 128 floats
  if (wc == 0 && l15 == 0) {
#pragma unroll
    for (int rf = 0; rf < 4; ++rf)
#pragma unroll
      for (int r = 0; r < 4; ++r) {
        const int rl = wr * 64 + rf * 16 + lgrp * 4 + r;
        sM[rl] = s16[rf][r]; tM[rl] = tv16[rf][r];
      }
  }
  __syncthreads();
  if (wc == 1 && l15 == 0) {
#pragma unroll
    for (int rf = 0; rf < 4; ++rf)
#pragma unroll
      for (int r = 0; r < 4; ++r) {
        const int rl = wr * 64 + rf * 16 + lgrp * 4 + r;
        part[(size_t)cb * BTOT + rowb + rl] =
            make_float2(sM[rl] + s16[rf][r], fmaxf(tM[rl], tv16[rf][r]));
      }
  }
}

// ---- combine 8 panel-partials -> loss, + hi-16 histogram ----
__global__ void combine_hist(const float2* __restrict__ part,
                             float* __restrict__ losses,
                             unsigned* __restrict__ hHi) {
  const int row = blockIdx.x * 256 + threadIdx.x;
  float s = 0.f, tv = NEG_BIG;
#pragma unroll
  for (int p = 0; p < 8; ++p) {
    const float2 v = part[(size_t)p * BTOT + row];
    s += v.x; tv = fmaxf(tv, v.y);
  }
  float loss = LN2 * (__builtin_amdgcn_logf(s) - tv);
  loss = fmaxf(loss, 0.f);
  losses[row] = loss;
  atomicAdd(&hHi[__float_as_uint(loss) >> 16], 1u);
}

// ---- level scan: find bin containing the k-th largest; 1 block x 256 threads ----
__global__ void scan_level(const unsigned* __restrict__ hist,
                           unsigned* __restrict__ state, const int level) {
  const int t = threadIdx.x;
  __shared__ unsigned sh[256];
  const unsigned k       = (level == 0) ? (unsigned)KSEL : state[1];
  const unsigned oldpref = (level == 0) ? 0u : state[0];

  unsigned gs = 0;
  const uint4* hp = (const uint4*)(hist + t * 256);
#pragma unroll 4
  for (int i = 0; i < 64; ++i) { const uint4 h = hp[i]; gs += h.x + h.y + h.z + h.w; }
  sh[t] = gs;
  __syncthreads();
  for (int off = 1; off < 256; off <<= 1) {   // inclusive suffix scan
    unsigned v = sh[t];
    if (t + off < 256) v += sh[t + off];
    __syncthreads();
    sh[t] = v;
    __syncthreads();
  }
  const unsigned incl  = sh[t];
  const unsigned above = (t < 255) ? sh[t + 1] : 0u;
  if (above < k && k <= incl) {
    unsigned kk = k - above;
    int bkt = 255;
    for (; bkt > 0; --bkt) {
      const unsigned c = hist[t * 256 + bkt];
      if (kk <= c) break;
      kk -= c;
    }
    const unsigned bin = (unsigned)(t * 256 + bkt);
    if (level == 0) { state[0] = bin << 16;      state[1] = kk; }
    else            { state[0] = oldpref | bin;  state[1] = kk; }
  }
}

__global__ void hist_lo(const float* __restrict__ losses,
                        const unsigned* __restrict__ state,
                        unsigned* __restrict__ hLo) {
  const unsigned pref = state[0] >> 16;
  const int i = blockIdx.x * 256 + threadIdx.x;
  const unsigned u = ((const unsigned*)losses)[i];
  if ((u >> 16) == pref) atomicAdd(&hLo[u & 0xFFFFu], 1u);
}

// ---- deterministic sum/count of values strictly greater than threshold ----
__global__ void ohem_sum(const float* __restrict__ losses,
                         const unsigned* __restrict__ state,
                         float* __restrict__ psum, unsigned* __restrict__ pcnt) {
  const unsigned ut = state[0];
  const int i = blockIdx.x * 256 + threadIdx.x;
  const float v = losses[i];
  const unsigned u = __float_as_uint(v);
  float    sv = (u > ut) ? v  : 0.f;
  unsigned sc = (u > ut) ? 1u : 0u;
#pragma unroll
  for (int st = 32; st >= 1; st >>= 1) {
    sv += __shfl_xor(sv, st, 64);
    sc += __shfl_xor(sc, st, 64);
  }
  __shared__ float    wsum[4];
  __shared__ unsigned wcnt[4];
  const int w = threadIdx.x >> 6;
  if ((threadIdx.x & 63) == 0) { wsum[w] = sv; wcnt[w] = sc; }
  __syncthreads();
  if (threadIdx.x == 0) {
    psum[blockIdx.x] = wsum[0] + wsum[1] + wsum[2] + wsum[3];
    pcnt[blockIdx.x] = wcnt[0] + wcnt[1] + wcnt[2] + wcnt[3];
  }
}

__global__ void ohem_final(const float* __restrict__ psum,
                           const unsigned* __restrict__ pcnt,
                           const unsigned* __restrict__ state,
                           float* __restrict__ out) {
  float    sv = psum[threadIdx.x];
  unsigned sc = pcnt[threadIdx.x];
#pragma unroll
  for (int st = 32; st >= 1; st >>= 1) {
    sv += __shfl_xor(sv, st, 64);
    sc += __shfl_xor(sc, st, 64);
  }
  __shared__ float    wsum[4];
  __shared__ unsigned wcnt[4];
  const int w = threadIdx.x >> 6;
  if ((threadIdx.x & 63) == 0) { wsum[w] = sv; wcnt[w] = sc; }
  __syncthreads();
  if (threadIdx.x == 0) {
    const float    sum = wsum[0] + wsum[1] + wsum[2] + wsum[3];
    const unsigned cnt = wcnt[0] + wcnt[1] + wcnt[2] + wcnt[3];
    const float t = __uint_as_float(state[0]);
    out[0] = (sum + (float)(KSEL - cnt) * t) / (float)KSEL;
  }
}

extern "C" void kernel_launch(void* const* d_in, const int* in_sizes, int n_in,
                              void* d_out, int out_size, void* d_ws, size_t ws_size,
                              hipStream_t stream) {
  const float* feat    = (const float*)d_in[0];
  const int*   targets = (const int*)d_in[1];
  const float* W       = (const float*)d_in[2];
  const float* b       = (const float*)d_in[3];
  float* out = (float*)d_out;

  char* ws = (char*)d_ws;
  unsigned short* Wg     = (unsigned short*)ws;              // 1 MiB (pre-swizzled tiles)
  float*          bp     = (float*)(ws + 1048576);           // 4 KiB
  float2*         part   = (float2*)(ws + 1052672);          // 4 MiB (8 panels x 65536 x float2)
  float*          losses = (float*)(ws + 5246976);           // 256 KiB
  unsigned*       hHi    = (unsigned*)(ws + 5509120);        // 256 KiB
  unsigned*       hLo    = (unsigned*)(ws + 5771264);        // 256 KiB (contiguous after hHi)
  unsigned*       state  = (unsigned*)(ws + 6033408);        // 256 B
  float*          psum   = (float*)(ws + 6033664);           // 1 KiB
  unsigned*       pcnt   = (unsigned*)(ws + 6034688);        // 1 KiB

  prep_all<<<385, 256, 0, stream>>>(W, b, Wg, bp, hHi);      // hHi..hLo zeroed
  ohem_gemm<<<4096, 256, 0, stream>>>(feat, targets, Wg, bp, part);
  combine_hist<<<256, 256, 0, stream>>>(part, losses, hHi);
  scan_level<<<1, 256, 0, stream>>>(hHi, state, 0);
  hist_lo<<<256, 256, 0, stream>>>(losses, state, hLo);
  scan_level<<<1, 256, 0, stream>>>(hLo, state, 1);
  ohem_sum<<<256, 256, 0, stream>>>(losses, state, psum, pcnt);
  ohem_final<<<1, 256, 0, stream>>>(psum, pcnt, state, out);
}